// Round 9
// baseline (26.971 us; speedup 1.0000x reference)
//
#include <hip/hip_runtime.h>

#define TT 2048
#define BB 4096
#define DROP_ROWS 11
#define NOUT (BB - DROP_ROWS)   /* 4085 output rows */
#define PERIOD 24
#define BLOCK 512
#define NWAVES 8
#define HALF 12
#define ROWS 4

typedef float nfloat4 __attribute__((ext_vector_type(4)));

// Raw barrier: drain LDS ops only; leave global loads/stores in flight.
#define BARRIER() asm volatile("s_waitcnt lgkmcnt(0)\n\ts_barrier" ::: "memory")

__global__ __launch_bounds__(BLOCK) void seasonal_decomp_kernel(
    const float* __restrict__ x, float* __restrict__ out) {
  // buf overlays: cs[0..2048] (cumsum) then sout[0..6143] (packed output).
  __shared__ float buf[6144];
  __shared__ float pp2[3][520];        // 512 slots + 8 pad -> reducer conflict-free
  __shared__ float wt[NWAVES];
  __shared__ float pmean[PERIOD];
  float* const cs = buf;
  float* const sout = buf;

  const int tid = threadIdx.x;
  const int lane = tid & 63;
  const int wave = tid >> 6;
  const int rbase = blockIdx.x * ROWS;

  // phase of this thread's first trend-stage element t0 = 256*wave + lane
  const int q0 = (256 * wave + lane) % 24;
  int mA, mB, mC;                      // phase-slot (p>>3) for classes A,B,C
  if (q0 < 8)       { mA = 0; mB = 2; mC = 1; }
  else if (q0 < 16) { mA = 1; mB = 0; mC = 2; }
  else              { mA = 2; mB = 1; mC = 0; }

  // initial prefetch of first row: one float4 per thread (512*16B = 8KB row)
  float4 v0;
  if (rbase < NOUT) {
    const float4* rx = (const float4*)(x + (size_t)(rbase + DROP_ROWS) * TT);
    v0 = rx[tid];
  }

  for (int r = 0; r < ROWS; ++r) {
    const int orow_i = rbase + r;
    const bool active = (orow_i < NOUT);   // uniform per block

    float s = 0.f, i = 0.f;
    if (active) {
      // ---- per-thread chunk sum + wave-level inclusive scan ----
      s = v0.x + v0.y + v0.z + v0.w;
      i = s;
      #pragma unroll
      for (int off = 1; off < 64; off <<= 1) {
        float t = __shfl_up(i, off, 64);
        if (lane >= off) i += t;
      }
      if (lane == 63) wt[wave] = i;
    }
    BARRIER();                             // A1: wt ready; prev row LDS done

    if (active) {
      float W = 0.f;
      #pragma unroll
      for (int w = 0; w < NWAVES; ++w)
        if (w < wave) W += wt[w];
      const float P = W + (i - s);         // cs[4*tid]
      float4 c;
      c.x = P; c.y = P + v0.x; c.z = c.y + v0.y; c.w = c.z + v0.z;
      ((float4*)cs)[tid] = c;
      if (tid == BLOCK - 1) cs[TT] = P + s;
    }

    // ---- prefetch NEXT row; flies across the lgkm-only barriers ----
    if (r + 1 < ROWS && rbase + r + 1 < NOUT) {
      const float4* rx =
          (const float4*)(x + (size_t)(rbase + r + 1 + DROP_ROWS) * TT);
      v0 = rx[tid];
    }
    BARRIER();                             // A2: cs ready

    float tr[4], sdr[4];
    if (active) {
      // ---- trend + detrended; wave-contiguous chunk t = 256*wave+64*j+lane ----
      float A = 0.f, B = 0.f, C2 = 0.f;
      #pragma unroll
      for (int j = 0; j < 4; ++j) {
        const int t = 256 * wave + 64 * j + lane;
        const float xt = cs[t + 1] - cs[t];
        float trv;
        if (t >= HALF && t < TT - HALF) {            // interior: count 25
          trv = (cs[t + HALF + 1] - cs[t - HALF]) * (1.0f / 25.0f);
        } else {
          const int a = (t - HALF < 0) ? 0 : t - HALF;
          const int e = (t + HALF + 1 > TT) ? TT : t + HALF + 1;
          trv = (cs[e] - cs[a]) / (float)(e - a);
        }
        tr[j] = trv;
        sdr[j] = xt - trv;
        if (j == 0 || j == 3) A += sdr[j];  // phase q0       (j%3==0)
        else if (j == 1) B += sdr[j];       // phase (q0+16)%24
        else C2 += sdr[j];                  // phase (q0+8)%24
      }
      pp2[mA][tid] = A;
      pp2[mB][tid] = B;
      pp2[mC][tid] = C2;
    }
    BARRIER();                             // C: pp2 ready

    if (active && tid < PERIOD) {
      const int c = tid & 7, m = tid >> 3;  // phase = 8m + c
      float sum = 0.f;
      #pragma unroll
      for (int k = 0; k < 64; ++k) sum += pp2[m][8 * k + c];
      pmean[tid] = sum * ((tid < 8) ? (1.0f / 86.f) : (1.0f / 85.f));
    }
    BARRIER();                             // D: pmean ready; cs dead

    if (active) {
      // ---- wave-local pack (stride-3 writes: ~2 lanes/bank = free) ----
      float* const mysout = sout + 768 * wave;
      int p = q0;
      #pragma unroll
      for (int j = 0; j < 4; ++j) {
        const int t64 = 64 * j + lane;
        const float pm = pmean[p];
        p += 16; if (p >= PERIOD) p -= PERIOD;   // (t+64) % 24
        mysout[3 * t64]     = tr[j];
        mysout[3 * t64 + 1] = pm;
        mysout[3 * t64 + 2] = sdr[j] - pm;
      }
      // ---- wave-local read-back + coalesced non-temporal float4 stores ----
      const nfloat4* so4 = (const nfloat4*)mysout;
      nfloat4* orow = (nfloat4*)(out + (size_t)orow_i * (TT * 3));
      #pragma unroll
      for (int j = 0; j < 3; ++j) {
        nfloat4 v = so4[64 * j + lane];
        __builtin_nontemporal_store(v, &orow[192 * wave + 64 * j + lane]);
      }
    }
  }
}

extern "C" void kernel_launch(void* const* d_in, const int* in_sizes, int n_in,
                              void* d_out, int out_size, void* d_ws, size_t ws_size,
                              hipStream_t stream) {
  const float* x = (const float*)d_in[0];
  float* out = (float*)d_out;
  const int grid = (NOUT + ROWS - 1) / ROWS;   // 1022 blocks, 4/CU, 32 waves/CU
  seasonal_decomp_kernel<<<grid, BLOCK, 0, stream>>>(x, out);
}